// Round 1
// baseline (147.930 us; speedup 1.0000x reference)
//
#include <hip/hip_runtime.h>

// SConv2dAvg: out[b,o,y,x] = sum_{c,kh,kw} in[b,c,2y+selh+kh,2x+selw+kw] * W[o,c,kh,kw] + bias[o]
// B=16 Cin=64 H=W=128 Cout=64 oh=ow=63 stride=2, fp32 in/out.
// Round 4: stage-2 is now a ZERO-STAGING direct-MFMA kernel.
//  - A fragment (8 contiguous bf16 channels) loaded straight from NHWC global;
//    identical byte pattern to the old LDS staging load, minus the round-trip.
//  - B fragment loaded straight from wgt_t (o,tap,c) — 73.7 KB, L2-resident.
//  - LDS only for the 16.6 KB epilogue transpose (LDO=65: read-side conflict-free).
//  - One barrier per block (epilogue), __launch_bounds__(256,4): 16 waves/CU.
// Stage-1 weight repack fused into the input repack kernel (blockIdx.y==H_ slice).

#define B_    16
#define CIN   64
#define H_    128
#define W_    128
#define COUT  64
#define OH    63
#define OW    63
#define NPIX  (OH * OW)      // 3969
#define KTOT  (CIN * 9)      // 576

typedef short  short8  __attribute__((ext_vector_type(8)));
typedef float  float4v __attribute__((ext_vector_type(4)));

__device__ inline short f2bf(float f) {     // RN-to-even fp32 -> bf16 bits
    union { float f; unsigned u; } x; x.f = f;
    unsigned r = x.u + 0x7fffu + ((x.u >> 16) & 1u);
    return (short)(r >> 16);
}

// ---------------- stage 1: input NCHW fp32 -> NHWC bf16  (+ fused weight repack) ----------------
__global__ __launch_bounds__(256)
void repack_bf16(const float* __restrict__ in, const float* __restrict__ wgt,
                 short* __restrict__ nhwc, short* __restrict__ wgt_t) {
    if (blockIdx.y == H_) {                 // weight duty: (o,c,tap) fp32 -> (o,tap,c) bf16
        const int bid = blockIdx.z * 2 + blockIdx.x;           // 0..31
        for (int e = bid * 256 + (int)threadIdx.x; e < COUT * KTOT; e += 32 * 256) {
            const int o   = e / KTOT;
            const int rem = e - o * KTOT;
            const int c   = rem / 9;
            const int tap = rem - c * 9;
            wgt_t[o * KTOT + tap * CIN + c] = f2bf(wgt[e]);
        }
        return;
    }

    __shared__ float T[64 * 65];            // T[c][w], pad 65
    const int tid = threadIdx.x;
    const int w0  = blockIdx.x * 64;
    const int h   = blockIdx.y;
    const int b   = blockIdx.z;

    {   // load 64c x 64w, coalesced along w
        const int w4 = tid & 15;
        const int cl = tid >> 4;
#pragma unroll
        for (int i = 0; i < 4; ++i) {
            const int c = cl + 16 * i;
            const float4 v = *(const float4*)&in[((b * CIN + c) * H_ + h) * W_ + w0 + 4 * w4];
            T[c * 65 + 4 * w4 + 0] = v.x;
            T[c * 65 + 4 * w4 + 1] = v.y;
            T[c * 65 + 4 * w4 + 2] = v.z;
            T[c * 65 + 4 * w4 + 3] = v.w;
        }
    }
    __syncthreads();
    {   // store: 8 channels/thread as one 16B bf16 vector, coalesced along c
        const int cg = tid & 7;             // channel group (8 ch)
        const int wl = tid >> 3;            // 0..31
#pragma unroll
        for (int i = 0; i < 2; ++i) {
            const int w = wl + 32 * i;
            short8 v;
#pragma unroll
            for (int t = 0; t < 8; ++t)
                v[t] = f2bf(T[(8 * cg + t) * 65 + w]);
            *(short8*)&nhwc[((b * H_ + h) * W_ + w0 + w) * CIN + 8 * cg] = v;
        }
    }
}

// ---------------- stage 2: direct-from-global MFMA implicit GEMM ----------------
// block: 16 pixels x 4 batches (M=64) x 64 Cout, 256 threads = 4 waves.
// Per wave: 18 A-loads + 72 B-loads (all 16B, immediate-offset) + 72 MFMA. No staging.
#define PIXT  16
#define BT    4
#define LDO   65    // epilogue staging stride (floats): read-side conflict-free

__global__ __launch_bounds__(256, 4)
void sconv2davg_mfma(const short* __restrict__ nhwc,
                     const short* __restrict__ wgt_t,
                     const float* __restrict__ bias,
                     const int* __restrict__ selh,
                     const int* __restrict__ selw,
                     float* __restrict__ out) {
    __shared__ __align__(16) float Ot[64 * LDO];      // 16.6 KB epilogue only

    const int tid = threadIdx.x;
    const int p0  = blockIdx.x * PIXT;
    const int b0  = blockIdx.y * BT;

    // MFMA lane decomposition
    const int ln = tid & 15;                // col within 16
    const int hl = (tid >> 4) & 3;          // k-quad: channels hl*8..hl*8+7
    const int wv = tid >> 6;                // wave id: M-strip rows 16*wv..+15

    // this lane's M row -> (pixel, batch)
    const int m  = 16 * wv + ln;
    const int pl = m >> 2;
    const int bl = m & 3;
    int p = p0 + pl;
    if (p > NPIX - 1) p = NPIX - 1;         // tail clamp; stores guarded
    const int y   = p / OW;
    const int x   = p - y * OW;
    const int ih0 = 2 * y + selh[p];
    const int iw0 = 2 * x + selw[p];

    // 3 A row-base pointers (kh=0..2); kw/cc folds into the 13-bit imm offset
    const short* A0 = &nhwc[(((b0 + bl) * H_ + ih0) * W_ + iw0) * CIN + hl * 8];
    const short* A1 = A0 + W_ * CIN;
    const short* A2 = A1 + W_ * CIN;
    // B base (j*16*KTOT exceeds imm range; compiler keeps 4 bases)
    const short* Bp = &wgt_t[ln * KTOT + hl * 8];

    float4v acc[4];
#pragma unroll
    for (int j = 0; j < 4; ++j) acc[j] = (float4v){0.f, 0.f, 0.f, 0.f};

#pragma unroll
    for (int cc = 0; cc < 2; ++cc) {
        const int c0 = cc * 32;
#pragma unroll
        for (int tap = 0; tap < 9; ++tap) {
            const int kh = tap / 3;
            const int kw = tap - 3 * kh;
            const short* Ar = (kh == 0) ? A0 : ((kh == 1) ? A1 : A2);
            const short8 a = *(const short8*)&Ar[kw * CIN + c0];
#pragma unroll
            for (int j = 0; j < 4; ++j) {
                const short8 b = *(const short8*)&Bp[(16 * j) * KTOT + tap * CIN + c0];
                acc[j] = __builtin_amdgcn_mfma_f32_16x16x32_bf16(a, b, acc[j], 0, 0, 0);
            }
        }
    }

    // epilogue: C/D layout col=ln, row=4*hl+r  ->  LDS  ->  coalesced rows of 16 p
#pragma unroll
    for (int j = 0; j < 4; ++j) {
        const float bv = bias[16 * j + ln];
#pragma unroll
        for (int r = 0; r < 4; ++r)
            Ot[(16 * wv + 4 * hl + r) * LDO + 16 * j + ln] = acc[j][r] + bv;
    }
    __syncthreads();
    {
        const int pp = tid & 15;            // pixel within tile (lanes 0..15 -> 64B runs)
        const int rr = tid >> 4;            // 0..15
        const int p2 = p0 + pp;
        if (p2 < NPIX) {
#pragma unroll
            for (int k = 0; k < 16; ++k) {
                const int rid = k * 16 + rr;        // 0..255 = b2*64+o
                const int b2  = rid >> 6;
                const int o   = rid & 63;
                out[((b0 + b2) * COUT + o) * NPIX + p2] = Ot[(pp * 4 + b2) * LDO + o];
            }
        }
    }
}

// ---------------- fallback (round-1 kernel) if ws too small ----------------
#define FKC   72
#define FLDA  76
__global__ __launch_bounds__(256, 4)
void sconv2davg_fallback(const float* __restrict__ in,
                         const float* __restrict__ wgt,
                         const float* __restrict__ bias,
                         const int* __restrict__ selh,
                         const int* __restrict__ selw,
                         float* __restrict__ out) {
    __shared__ float As[64 * FLDA];
    __shared__ float Ws[64 * FLDA];
    __shared__ int hb_s[4], wb_s[4];
    const int tid = threadIdx.x;
    const int p0  = blockIdx.x * 4;
    if (tid < 4) {
        int p = p0 + tid;
        if (p > NPIX - 1) p = NPIX - 1;
        int y = p / OW;
        int x = p - y * OW;
        hb_s[tid] = 2 * y + selh[p];
        wb_s[tid] = 2 * x + selw[p];
    }
    __syncthreads();
    const int tn = tid & 15, tm = tid >> 4;
    float acc[4][4];
#pragma unroll
    for (int i = 0; i < 4; ++i)
#pragma unroll
        for (int j = 0; j < 4; ++j) acc[i][j] = 0.0f;
    for (int cc = 0; cc < 8; ++cc) {
        const int c0 = cc * 8;
#pragma unroll
        for (int it = 0; it < 18; ++it) {
            int idx = tid + it * 256;
            int m = idx / FKC, rem = idx - m * FKC;
            int cl = rem / 9, r = rem - cl * 9;
            int kh = r / 3, kw = r - kh * 3;
            As[m * FLDA + rem] =
                in[((((m & 15) * CIN) + (c0 + cl)) * H_ + hb_s[m >> 4] + kh) * W_ + wb_s[m >> 4] + kw];
        }
#pragma unroll
        for (int it = 0; it < 18; ++it) {
            int idx = tid + it * 256;
            int o = idx / FKC, kk = idx - o * FKC;
            Ws[o * FLDA + kk] = wgt[o * KTOT + cc * FKC + kk];
        }
        __syncthreads();
#pragma unroll 2
        for (int k0 = 0; k0 < FKC; k0 += 4) {
            float4 a[4], w[4];
#pragma unroll
            for (int i = 0; i < 4; ++i) a[i] = *(const float4*)&As[(4 * tm + i) * FLDA + k0];
#pragma unroll
            for (int j = 0; j < 4; ++j) w[j] = *(const float4*)&Ws[(tn + 16 * j) * FLDA + k0];
#pragma unroll
            for (int i = 0; i < 4; ++i)
#pragma unroll
                for (int j = 0; j < 4; ++j) {
                    acc[i][j] += a[i].x * w[j].x; acc[i][j] += a[i].y * w[j].y;
                    acc[i][j] += a[i].z * w[j].z; acc[i][j] += a[i].w * w[j].w;
                }
        }
        __syncthreads();
    }
    const int p = p0 + (tm >> 2);
    if (p < NPIX) {
#pragma unroll
        for (int i = 0; i < 4; ++i) {
            int b = (tm & 3) * 4 + i;
#pragma unroll
            for (int j = 0; j < 4; ++j)
                out[((b * COUT) + tn + 16 * j) * NPIX + p] = acc[i][j] + bias[tn + 16 * j];
        }
    }
}

extern "C" void kernel_launch(void* const* d_in, const int* in_sizes, int n_in,
                              void* d_out, int out_size, void* d_ws, size_t ws_size,
                              hipStream_t stream) {
    const float* in   = (const float*)d_in[0];
    const float* wgt  = (const float*)d_in[1];
    const float* bias = (const float*)d_in[2];
    const int*   selh = (const int*)d_in[3];
    const int*   selw = (const int*)d_in[4];
    float* out = (float*)d_out;

    const size_t nhwc_elems = (size_t)B_ * H_ * W_ * CIN;            // 16.7M bf16
    const size_t need = (nhwc_elems + (size_t)COUT * KTOT) * 2;      // ~33.6 MB

    if (ws_size >= need) {
        short* nhwc  = (short*)d_ws;
        short* wgt_t = nhwc + nhwc_elems;
        // y==H_ slice of the grid does the weight repack (32 blocks)
        repack_bf16<<<dim3(W_ / 64, H_ + 1, B_), 256, 0, stream>>>(in, wgt, nhwc, wgt_t);
        const int ptiles = (NPIX + PIXT - 1) / PIXT;                 // 249
        sconv2davg_mfma<<<dim3(ptiles, B_ / BT), 256, 0, stream>>>(
            nhwc, wgt_t, bias, selh, selw, out);
    } else {
        sconv2davg_fallback<<<(NPIX + 3) / 4, 256, 0, stream>>>(
            in, wgt, bias, selh, selw, out);
    }
}

// Round 2
// 126.238 us; speedup vs baseline: 1.1718x; 1.1718x over previous
//
#include <hip/hip_runtime.h>

// SConv2dAvg: out[b,o,y,x] = sum_{c,kh,kw} in[b,c,2y+selh+kh,2x+selw+kw] * W[o,c,kh,kw] + bias[o]
// B=16 Cin=64 H=W=128 Cout=64 oh=ow=63 stride=2, fp32 in/out.
// Round 5: latency-proof stage 2.
//  - Wave wv owns Cout group 16*wv..+15, ALL 64 M rows. Its weights (18 x short8
//    = 144 VGPRs) are loaded ONCE into registers: no per-MFMA B latency, no B LDS.
//  - A tile [u=cc*9+tap][64 m][32 ch] (73.7 KB) staged by global_load_lds width=16
//    (async, no VGPR round trip); wave wv stages its own 16 m-rows; LDS dest is
//    linear in lane (wave-uniform base + lane*16) as the HW requires.
//  - ONE vmcnt drain (the single pre-compute barrier). Compute = 18 K-steps of
//    4x ds_read_b128 (contiguous 1KB/wave, conflict-free) + 4 MFMA. 3 barriers total.

#define B_    16
#define CIN   64
#define H_    128
#define W_    128
#define COUT  64
#define OH    63
#define OW    63
#define NPIX  (OH * OW)      // 3969
#define KTOT  (CIN * 9)      // 576

typedef short  short8  __attribute__((ext_vector_type(8)));
typedef float  float4v __attribute__((ext_vector_type(4)));

__device__ inline short f2bf(float f) {     // RN-to-even fp32 -> bf16 bits
    union { float f; unsigned u; } x; x.f = f;
    unsigned r = x.u + 0x7fffu + ((x.u >> 16) & 1u);
    return (short)(r >> 16);
}

// ---------------- stage 1: input NCHW fp32 -> NHWC bf16  (+ fused weight repack) ----------------
__global__ __launch_bounds__(256)
void repack_bf16(const float* __restrict__ in, const float* __restrict__ wgt,
                 short* __restrict__ nhwc, short* __restrict__ wgt_t) {
    if (blockIdx.y == H_) {                 // weight duty: (o,c,tap) fp32 -> (o,tap,c) bf16
        const int bid = blockIdx.z * 2 + blockIdx.x;           // 0..31
        for (int e = bid * 256 + (int)threadIdx.x; e < COUT * KTOT; e += 32 * 256) {
            const int o   = e / KTOT;
            const int rem = e - o * KTOT;
            const int c   = rem / 9;
            const int tap = rem - c * 9;
            wgt_t[o * KTOT + tap * CIN + c] = f2bf(wgt[e]);
        }
        return;
    }

    __shared__ float T[64 * 65];            // T[c][w], pad 65
    const int tid = threadIdx.x;
    const int w0  = blockIdx.x * 64;
    const int h   = blockIdx.y;
    const int b   = blockIdx.z;

    {   // load 64c x 64w, coalesced along w
        const int w4 = tid & 15;
        const int cl = tid >> 4;
#pragma unroll
        for (int i = 0; i < 4; ++i) {
            const int c = cl + 16 * i;
            const float4 v = *(const float4*)&in[((b * CIN + c) * H_ + h) * W_ + w0 + 4 * w4];
            T[c * 65 + 4 * w4 + 0] = v.x;
            T[c * 65 + 4 * w4 + 1] = v.y;
            T[c * 65 + 4 * w4 + 2] = v.z;
            T[c * 65 + 4 * w4 + 3] = v.w;
        }
    }
    __syncthreads();
    {   // store: 8 channels/thread as one 16B bf16 vector, coalesced along c
        const int cg = tid & 7;             // channel group (8 ch)
        const int wl = tid >> 3;            // 0..31
#pragma unroll
        for (int i = 0; i < 2; ++i) {
            const int w = wl + 32 * i;
            short8 v;
#pragma unroll
            for (int t = 0; t < 8; ++t)
                v[t] = f2bf(T[(8 * cg + t) * 65 + w]);
            *(short8*)&nhwc[((b * H_ + h) * W_ + w0 + w) * CIN + 8 * cg] = v;
        }
    }
}

// ---------------- stage 2: B-in-registers, A-async-LDS MFMA implicit GEMM ----------------
// block: 16 pixels x 4 batches (M=64) x 64 Cout, 256 threads = 4 waves.
#define PIXT  16
#define BT    4
#define LDO   65    // epilogue staging stride (floats)

__global__ __launch_bounds__(256, 2)
void sconv2davg_mfma(const short* __restrict__ nhwc,
                     const short* __restrict__ wgt_t,
                     const float* __restrict__ bias,
                     const int* __restrict__ selh,
                     const int* __restrict__ selw,
                     float* __restrict__ out) {
    __shared__ __align__(16) short As[18 * 2048];   // [u][m=64][32ch]  73.7 KB

    const int tid = threadIdx.x;
    const int p0  = blockIdx.x * PIXT;
    const int b0  = blockIdx.y * BT;

    const int ln = tid & 15;                // MFMA col within 16
    const int hl = (tid >> 4) & 3;          // k-quad: channels hl*8..hl*8+7
    const int wv = tid >> 6;                // wave id = Cout group
    const int l  = tid & 63;                // lane

    // ---- B: this wave's full-K weight panel -> 18 x short8 = 144 VGPRs ----
    const short* Bp = &wgt_t[(16 * wv + ln) * KTOT + hl * 8];
    short8 Bv[18];
#pragma unroll
    for (int u = 0; u < 18; ++u) {
        const int cc = u / 9, tap = u - 9 * (u / 9);
        Bv[u] = *(const short8*)&Bp[tap * CIN + cc * 32];
    }

    // ---- A: async stage; wave wv stages m = 16*wv .. 16*wv+15 for all 18 u ----
    {
        const int mst = 16 * wv + (l >> 2);     // this lane's staged M row
        const int pl  = mst >> 2;
        const int bl  = mst & 3;
        int p = p0 + pl;
        if (p > NPIX - 1) p = NPIX - 1;         // tail clamp; stores guarded
        const int y   = p / OW;
        const int x   = p - y * OW;
        const int ih0 = 2 * y + selh[p];
        const int iw0 = 2 * x + selw[p];
        const short* src0 =
            &nhwc[(((b0 + bl) * H_ + ih0) * W_ + iw0) * CIN + (l & 3) * 8];
        short* dst0 = &As[wv * 512] + l * 8;    // linear-in-lane LDS dest
#pragma unroll
        for (int u = 0; u < 18; ++u) {
            const int cc = u / 9, tap = u - 9 * (u / 9);
            const int kh = tap / 3, kw = tap - 3 * (tap / 3);
            __builtin_amdgcn_global_load_lds(
                (const __attribute__((address_space(1))) void*)
                    (src0 + kh * (W_ * CIN) + kw * CIN + cc * 32),
                (__attribute__((address_space(3))) void*)(dst0 + u * 2048),
                16, 0, 0);
        }
    }
    __syncthreads();                            // single vmcnt drain (B regs + A LDS)

    // ---- compute: 18 K-steps x (4 ds_read_b128 + 4 MFMA), B from regs ----
    float4v acc[4];
#pragma unroll
    for (int i = 0; i < 4; ++i) acc[i] = (float4v){0.f, 0.f, 0.f, 0.f};
#pragma unroll
    for (int u = 0; u < 18; ++u) {
#pragma unroll
        for (int i = 0; i < 4; ++i) {
            const short8 a = *(const short8*)
                &As[u * 2048 + (16 * i + ln) * 32 + hl * 8];
            acc[i] = __builtin_amdgcn_mfma_f32_16x16x32_bf16(a, Bv[u], acc[i], 0, 0, 0);
        }
    }
    __syncthreads();                            // all A reads done; reuse As as Ot

    // ---- epilogue: C/D col=ln, row=4*hl+r; m = 16*i + 4*hl + r; o = 16*wv + ln ----
    float* Ot = (float*)As;
    const float bv = bias[16 * wv + ln];
#pragma unroll
    for (int i = 0; i < 4; ++i)
#pragma unroll
        for (int r = 0; r < 4; ++r)
            Ot[(16 * i + 4 * hl + r) * LDO + 16 * wv + ln] = acc[i][r] + bv;
    __syncthreads();
    {
        const int pp = tid & 15;                // pixel within tile
        const int rr = tid >> 4;                // 0..15
        const int p2 = p0 + pp;
        if (p2 < NPIX) {
#pragma unroll
            for (int k = 0; k < 16; ++k) {
                const int rid = k * 16 + rr;    // 0..255 = b2*64 + o
                const int b2  = rid >> 6;
                const int o   = rid & 63;
                out[((b0 + b2) * COUT + o) * NPIX + p2] = Ot[(pp * 4 + b2) * LDO + o];
            }
        }
    }
}

// ---------------- fallback (round-1 kernel) if ws too small ----------------
#define FKC   72
#define FLDA  76
__global__ __launch_bounds__(256, 4)
void sconv2davg_fallback(const float* __restrict__ in,
                         const float* __restrict__ wgt,
                         const float* __restrict__ bias,
                         const int* __restrict__ selh,
                         const int* __restrict__ selw,
                         float* __restrict__ out) {
    __shared__ float As[64 * FLDA];
    __shared__ float Ws[64 * FLDA];
    __shared__ int hb_s[4], wb_s[4];
    const int tid = threadIdx.x;
    const int p0  = blockIdx.x * 4;
    if (tid < 4) {
        int p = p0 + tid;
        if (p > NPIX - 1) p = NPIX - 1;
        int y = p / OW;
        int x = p - y * OW;
        hb_s[tid] = 2 * y + selh[p];
        wb_s[tid] = 2 * x + selw[p];
    }
    __syncthreads();
    const int tn = tid & 15, tm = tid >> 4;
    float acc[4][4];
#pragma unroll
    for (int i = 0; i < 4; ++i)
#pragma unroll
        for (int j = 0; j < 4; ++j) acc[i][j] = 0.0f;
    for (int cc = 0; cc < 8; ++cc) {
        const int c0 = cc * 8;
#pragma unroll
        for (int it = 0; it < 18; ++it) {
            int idx = tid + it * 256;
            int m = idx / FKC, rem = idx - m * FKC;
            int cl = rem / 9, r = rem - cl * 9;
            int kh = r / 3, kw = r - kh * 3;
            As[m * FLDA + rem] =
                in[((((m & 15) * CIN) + (c0 + cl)) * H_ + hb_s[m >> 4] + kh) * W_ + wb_s[m >> 4] + kw];
        }
#pragma unroll
        for (int it = 0; it < 18; ++it) {
            int idx = tid + it * 256;
            int o = idx / FKC, kk = idx - o * FKC;
            Ws[o * FLDA + kk] = wgt[o * KTOT + cc * FKC + kk];
        }
        __syncthreads();
#pragma unroll 2
        for (int k0 = 0; k0 < FKC; k0 += 4) {
            float4 a[4], w[4];
#pragma unroll
            for (int i = 0; i < 4; ++i) a[i] = *(const float4*)&As[(4 * tm + i) * FLDA + k0];
#pragma unroll
            for (int j = 0; j < 4; ++j) w[j] = *(const float4*)&Ws[(tn + 16 * j) * FLDA + k0];
#pragma unroll
            for (int i = 0; i < 4; ++i)
#pragma unroll
                for (int j = 0; j < 4; ++j) {
                    acc[i][j] += a[i].x * w[j].x; acc[i][j] += a[i].y * w[j].y;
                    acc[i][j] += a[i].z * w[j].z; acc[i][j] += a[i].w * w[j].w;
                }
        }
        __syncthreads();
    }
    const int p = p0 + (tm >> 2);
    if (p < NPIX) {
#pragma unroll
        for (int i = 0; i < 4; ++i) {
            int b = (tm & 3) * 4 + i;
#pragma unroll
            for (int j = 0; j < 4; ++j)
                out[((b * COUT) + tn + 16 * j) * NPIX + p] = acc[i][j] + bias[tn + 16 * j];
        }
    }
}

extern "C" void kernel_launch(void* const* d_in, const int* in_sizes, int n_in,
                              void* d_out, int out_size, void* d_ws, size_t ws_size,
                              hipStream_t stream) {
    const float* in   = (const float*)d_in[0];
    const float* wgt  = (const float*)d_in[1];
    const float* bias = (const float*)d_in[2];
    const int*   selh = (const int*)d_in[3];
    const int*   selw = (const int*)d_in[4];
    float* out = (float*)d_out;

    const size_t nhwc_elems = (size_t)B_ * H_ * W_ * CIN;            // 16.7M bf16
    const size_t need = (nhwc_elems + (size_t)COUT * KTOT) * 2;      // ~33.6 MB

    if (ws_size >= need) {
        short* nhwc  = (short*)d_ws;
        short* wgt_t = nhwc + nhwc_elems;
        // y==H_ slice of the grid does the weight repack (32 blocks)
        repack_bf16<<<dim3(W_ / 64, H_ + 1, B_), 256, 0, stream>>>(in, wgt, nhwc, wgt_t);
        const int ptiles = (NPIX + PIXT - 1) / PIXT;                 // 249
        sconv2davg_mfma<<<dim3(ptiles, B_ / BT), 256, 0, stream>>>(
            nhwc, wgt_t, bias, selh, selw, out);
    } else {
        sconv2davg_fallback<<<(NPIX + 3) / 4, 256, 0, stream>>>(
            in, wgt, bias, selh, selw, out);
    }
}